// Round 6
// baseline (561.083 us; speedup 1.0000x reference)
//
#include <hip/hip_runtime.h>
#include <math.h>

#define L_ 384
#define R_ 128
#define D_ 128
#define H_ 8
#define DH_ 64
#define INNER_ 512

typedef __bf16 bf16x8 __attribute__((ext_vector_type(8)));
typedef float f32x4 __attribute__((ext_vector_type(4)));

typedef const __attribute__((address_space(1))) void* as1cv;
typedef __attribute__((address_space(3))) void* as3v;
__device__ __forceinline__ void gll16(const void* g, void* l) {
  __builtin_amdgcn_global_load_lds((as1cv)g, (as3v)l, 16, 0, 0);
}

__device__ __forceinline__ float wred_sum(float v) {
#pragma unroll
  for (int o = 32; o > 0; o >>= 1) v += __shfl_xor(v, o, 64);
  return v;
}
__device__ __forceinline__ float wred_max(float v) {
#pragma unroll
  for (int o = 32; o > 0; o >>= 1) v = fmaxf(v, __shfl_xor(v, o, 64));
  return v;
}

// ---------------------------------------------------------------------------
// prep: m fp32->bf16 (blocks 0..3071) + all weight transposes (blocks 3072..3207)
// ---------------------------------------------------------------------------
__global__ __launch_bounds__(256) void prep_kernel(
    const float* __restrict__ m, __bf16* __restrict__ m_bf,
    const float* __restrict__ Wq_w, const float* __restrict__ Wkv_w,
    const float* __restrict__ Wq_h, const float* __restrict__ Wkv_h,
    const float* __restrict__ Wo_w, const float* __restrict__ Wo_h,
    const float* __restrict__ Wsk, const float* __restrict__ Wsq,
    __bf16* __restrict__ WTw, __bf16* __restrict__ WThqk,
    __bf16* __restrict__ WTvh, __bf16* __restrict__ WoTw,
    __bf16* __restrict__ WoTh, __bf16* __restrict__ WskT,
    __bf16* __restrict__ WsqT) {
  __shared__ float Ls[64 * 65];
  int b = blockIdx.x;
  int t = threadIdx.x;
  if (b < 3072) {
    int i = b * 256 + t;  // < 786432
    float4 a = *(const float4*)(m + (size_t)i * 8);
    float4 c = *(const float4*)(m + (size_t)i * 8 + 4);
    bf16x8 o;
    o[0] = (__bf16)a.x; o[1] = (__bf16)a.y; o[2] = (__bf16)a.z; o[3] = (__bf16)a.w;
    o[4] = (__bf16)c.x; o[5] = (__bf16)c.y; o[6] = (__bf16)c.z; o[7] = (__bf16)c.w;
    *(uint4*)(m_bf + (size_t)i * 8) = __builtin_bit_cast(uint4, o);
    return;
  }
  int j = b - 3072;
  const float* src; __bf16* dst; int Kd, Ns, noff, gx, base;
  if (j < 16)       { src = Wq_w;  dst = WTw;             Kd = 128; Ns = 512;  noff = 0;   gx = 8;  base = 0; }
  else if (j < 48)  { src = Wkv_w; dst = WTw + 512 * 128; Kd = 128; Ns = 1024; noff = 0;   gx = 16; base = 16; }
  else if (j < 64)  { src = Wq_h;  dst = WThqk;           Kd = 128; Ns = 512;  noff = 0;   gx = 8;  base = 48; }
  else if (j < 80)  { src = Wkv_h; dst = WThqk + 512 * 128; Kd = 128; Ns = 1024; noff = 0; gx = 8;  base = 64; }
  else if (j < 96)  { src = Wkv_h; dst = WTvh;            Kd = 128; Ns = 1024; noff = 512; gx = 8;  base = 80; }
  else if (j < 112) { src = Wo_w;  dst = WoTw;            Kd = 512; Ns = 128;  noff = 0;   gx = 2;  base = 96; }
  else if (j < 128) { src = Wo_h;  dst = WoTh;            Kd = 512; Ns = 128;  noff = 0;   gx = 2;  base = 112; }
  else if (j < 132) { src = Wsk;   dst = WskT;            Kd = 128; Ns = 128;  noff = 0;   gx = 2;  base = 128; }
  else              { src = Wsq;   dst = WsqT;            Kd = 128; Ns = 128;  noff = 0;   gx = 2;  base = 132; }
  int jl = j - base;
  int n0 = (jl % gx) * 64, k0 = (jl / gx) * 64;
#pragma unroll
  for (int u = 0; u < 4; ++u) {
    int flat = t + 256 * u;
    int kr = flat >> 4, nc = (flat & 15) * 4;
    float4 v = *(const float4*)&src[(size_t)(k0 + kr) * Ns + noff + n0 + nc];
    Ls[kr * 65 + nc + 0] = v.x;
    Ls[kr * 65 + nc + 1] = v.y;
    Ls[kr * 65 + nc + 2] = v.z;
    Ls[kr * 65 + nc + 3] = v.w;
  }
  __syncthreads();
#pragma unroll
  for (int u = 0; u < 2; ++u) {
    int flat = t + 256 * u;
    int nr = flat >> 3, kc = (flat & 7) * 8;
    bf16x8 o;
#pragma unroll
    for (int q = 0; q < 8; ++q) o[q] = (__bf16)Ls[(kc + q) * 65 + nr];
    *(uint4*)&dst[(size_t)(n0 + nr) * Kd + k0 + kc] = __builtin_bit_cast(uint4, o);
  }
}

// ---------------------------------------------------------------------------
// bf16 MFMA GEMM, 128x128 tile, BK=64, 256 threads (4 waves 2x2), 16x16x32 mfma.
// global_load_lds (16B) staging into unpadded XOR-swizzled LDS tiles.
// MODE 0: PROJ_W   A=m_bf gathered (l,r), B=WTw, C->q/k/v w-layout bf16
// MODE 1: PROJ_H   A=m_bf, B=WThqk, C->qh (tie-prescaled!) / kh h-layout bf16
// MODE 2: DOTS     pure NT GEMM, 1D XCD-swizzled grid, split-K partials fp32
// MODE 3: OH       A=attnb[h][L][L], B=vt[h][n][L], C->ob bf16
// MODE 4: OUT_W    C = 0.5*(acc+bias) -> out fp32
// MODE 5: OUT_H    C += 0.5*(acc+bias) -> out fp32
// MODE 6: PROJ_VT  A=WTvh, B=m_bf rows, C->vt bf16 (transposed v)
// MODE 8: TIE PROJ ks (y<384) / qs (y>=384, B=O2, bias=tie) -> bf16 [p][128]
// ---------------------------------------------------------------------------
template <int MODE>
__global__ __launch_bounds__(256) void mm_k(
    const __bf16* __restrict__ A, const __bf16* __restrict__ B,
    const float* __restrict__ bias, const float* __restrict__ tie,
    __bf16* __restrict__ O0, __bf16* __restrict__ O1, __bf16* __restrict__ O2,
    float* __restrict__ F0,
    int K, int c0, int Rc, int KT, int firstChunk, int S) {
  __shared__ __bf16 As[128 * 64];
  __shared__ __bf16 Bs[128 * 64];
  const int t = threadIdx.x;
  const int lane = t & 63, w = t >> 6;
  const int wm = w >> 1, wn = w & 1;
  int n0, m0, h = 0, s = 0, kOff = 0;
  const int bz = blockIdx.z;
  if (MODE == 2) {
    int b = blockIdx.x;
    int xcd = b & 7, t2 = b >> 3;
    int i3 = t2 % 3, slot = t2 / 3;
    int g = xcd * (gridDim.x / 24) + slot;
    n0 = i3 * 128;
    m0 = (g % 3) * 128;
    int z = g / 3;
    h = z / S; s = z % S; kOff = s * K;
  } else {
    n0 = blockIdx.x * 128;
    m0 = blockIdx.y * 128;
    if (MODE == 3) h = bz;
  }
  const int pbase = (MODE == 8 && m0 >= 49152) ? 49152 : 0;
  const __bf16* Bmat = (MODE == 8 && pbase) ? (const __bf16*)O2 : B;

  f32x4 acc[4][4];
#pragma unroll
  for (int i = 0; i < 4; ++i)
#pragma unroll
    for (int j = 0; j < 4; ++j) acc[i][j] = (f32x4){0.f, 0.f, 0.f, 0.f};

  const int row8 = lane >> 3, ch = lane & 7;
  const int cg = ch ^ row8;          // global chunk fetched into slot ch
  for (int k0 = 0; k0 < K; k0 += 64) {
    int kc = k0 + (cg << 3);
#pragma unroll
    for (int u = 0; u < 4; ++u) {
      int row = (w << 5) + (u << 3) + row8;
      int p = m0 + row;
      const __bf16* ap;
      if (MODE == 0) { int lrel = p >> 7, rr = p & 127;
        ap = A + ((size_t)(rr * L_ + c0 + lrel)) * 128 + kc; }
      else if (MODE == 1) ap = A + ((size_t)(c0 * L_ + p)) * 128 + kc;
      else if (MODE == 2) ap = A + ((size_t)(h * L_ + p)) * KT + kOff + kc;
      else if (MODE == 3) ap = A + ((size_t)(h * L_ + p)) * L_ + kc;
      else if (MODE == 4) ap = A + (size_t)p * INNER_ + kc;
      else if (MODE == 5) { int rrel = p / L_, l = p - rrel * L_;
        ap = A + (((size_t)((k0 >> 6) * L_ + l)) * Rc + rrel) * 64 + (cg << 3); }
      else if (MODE == 8) ap = A + (size_t)(p - pbase) * 128 + kc;
      else ap = A + (size_t)p * 128 + kc;
      gll16(ap, &As[((w << 5) + (u << 3)) * 64]);
      int n = n0 + row;
      const __bf16* bp;
      if (MODE == 0 || MODE == 1 || MODE == 8) bp = Bmat + (size_t)n * 128 + kc;
      else if (MODE == 2) bp = B + ((size_t)(h * L_ + n)) * KT + kOff + kc;
      else if (MODE == 3) bp = B + ((size_t)(h * Rc * 64 + n)) * L_ + kc;
      else if (MODE == 4 || MODE == 5) bp = B + (size_t)n * INNER_ + kc;
      else bp = B + ((size_t)((c0 + bz) * L_ + n)) * 128 + kc;
      gll16(bp, &Bs[((w << 5) + (u << 3)) * 64]);
    }
    __syncthreads();
    {
      int lc = lane & 15, lg = lane >> 4, sw = lc & 7;
#pragma unroll
      for (int kt = 0; kt < 2; ++kt) {
        int sl = ((kt << 2) + lg) ^ sw;
        bf16x8 af[4], bfr[4];
#pragma unroll
        for (int i = 0; i < 4; ++i) {
          af[i] = *(const bf16x8*)&As[(wm * 64 + i * 16 + lc) * 64 + sl * 8];
          bfr[i] = *(const bf16x8*)&Bs[(wn * 64 + i * 16 + lc) * 64 + sl * 8];
        }
#pragma unroll
        for (int i = 0; i < 4; ++i)
#pragma unroll
          for (int j = 0; j < 4; ++j)
            acc[i][j] = __builtin_amdgcn_mfma_f32_16x16x32_bf16(af[i], bfr[j], acc[i][j], 0, 0, 0);
      }
    }
    __syncthreads();
  }

  int lce = lane & 15, lr4 = (lane >> 4) << 2;
#pragma unroll
  for (int i = 0; i < 4; ++i) {
#pragma unroll
    for (int j = 0; j < 4; ++j) {
#pragma unroll
      for (int g = 0; g < 4; ++g) {
        int pm = m0 + wm * 64 + i * 16 + lr4 + g;
        int pn = n0 + wn * 64 + j * 16 + lce;
        float v = acc[i][j][g];
        if (MODE == 0) {
          __bf16* buf;
          int nn = pn;
          if (nn < 512) buf = O0;
          else if (nn < 1024) { buf = O1; nn -= 512; }
          else { buf = O2; nn -= 1024; }
          int hh = nn >> 6, dh = nn & 63;
          int lrel = pm >> 7, rr = pm & 127;
          buf[(((size_t)(lrel * H_ + hh)) * R_ + rr) * 64 + dh] = (__bf16)v;
        } else if (MODE == 1) {
          int nn = pn;
          int rrel = pm / L_, l = pm - rrel * L_;
          if (nn < 512) {  // qh: fold tie weight
            int hh = nn >> 6, dh = nn & 63;
            float tw = tie[((size_t)(l * H_ + hh)) * R_ + c0 + rrel];
            O0[(((size_t)(hh * L_ + l)) * Rc + rrel) * 64 + dh] = (__bf16)(v * tw);
          } else {
            nn -= 512;
            int hh = nn >> 6, dh = nn & 63;
            O1[(((size_t)(hh * L_ + l)) * Rc + rrel) * 64 + dh] = (__bf16)v;
          }
        } else if (MODE == 2) {
          float* ptr = F0 + ((size_t)(s * H_ + h)) * (L_ * L_) + (size_t)pm * L_ + pn;
          float val = 0.125f * v;
          if (firstChunk) *ptr = val;
          else *ptr += val;
        } else if (MODE == 3) {
          O0[((size_t)(h * L_ + pm)) * ((size_t)Rc * 64) + pn] = (__bf16)v;
        } else if (MODE == 4) {
          int lrel = pm >> 7, rr = pm & 127;
          F0[((size_t)(rr * L_ + c0 + lrel)) * 128 + pn] = 0.5f * (v + bias[pn]);
        } else if (MODE == 5) {
          int rrel = pm / L_, l = pm - rrel * L_;
          float* ptr = F0 + ((size_t)((c0 + rrel) * L_ + l)) * 128 + pn;
          *ptr += 0.5f * (v + bias[pn]);
        } else if (MODE == 8) {
          const float* bb = pbase ? tie : bias;
          __bf16* dst = pbase ? O1 : O0;
          dst[(size_t)(pm - pbase) * 128 + pn] = (__bf16)(v + bb[pn]);
        } else {
          O0[(((size_t)((pm >> 6) * Rc + bz)) * 64 + (pm & 63)) * (size_t)L_ + pn] = (__bf16)v;
        }
      }
    }
  }
}

// ---------------------------------------------------------------------------
// tie softmax (bf16 inputs)
// ---------------------------------------------------------------------------
__global__ __launch_bounds__(128) void tie_kernel(const __bf16* __restrict__ qs,
                                                  const __bf16* __restrict__ ks,
                                                  float* __restrict__ wtie) {
  int bid = blockIdx.x;
  int l = bid >> 3, h = bid & 7;
  int r = threadIdx.x;
  int wid = r >> 6;
  const __bf16* qp = qs + (size_t)l * 128 + h * 16;
  const __bf16* kp = ks + ((size_t)r * L_ + l) * 128 + h * 16;
  bf16x8 q0 = *(const bf16x8*)qp;
  bf16x8 q1 = *(const bf16x8*)(qp + 8);
  bf16x8 k0 = *(const bf16x8*)kp;
  bf16x8 k1 = *(const bf16x8*)(kp + 8);
  float s = 0.f;
#pragma unroll
  for (int i = 0; i < 8; ++i)
    s += (float)q0[i] * (float)k0[i] + (float)q1[i] * (float)k1[i];
  s *= 0.25f;
  __shared__ float sm[2], ss[2];
  float wm = wred_max(s);
  if ((r & 63) == 0) sm[wid] = wm;
  __syncthreads();
  float mx = fmaxf(sm[0], sm[1]);
  float e = __expf(s - mx);
  float wsum = wred_sum(e);
  if ((r & 63) == 0) ss[wid] = wsum;
  __syncthreads();
  float tot = ss[0] + ss[1];
  wtie[((size_t)l * H_ + h) * R_ + r] = e / tot;
}

// ---------------------------------------------------------------------------
// pair LN + Wpair -> pb[h][i][j]. One THREAD per (i,j); no cross-lane ops.
// ---------------------------------------------------------------------------
__global__ __launch_bounds__(256) void lnpb_kernel(const float* __restrict__ pair,
                                                   const float* __restrict__ g,
                                                   const float* __restrict__ b,
                                                   const float* __restrict__ wp,
                                                   float* __restrict__ pb) {
  __shared__ float gws[1024];
  __shared__ float c1s[8], c2s[8];
  int t = threadIdx.x;
#pragma unroll
  for (int u = 0; u < 4; ++u) {
    int idx = t * 4 + u;
    int d = idx >> 3, h = idx & 7;
    gws[idx] = g[d] * wp[d * 8 + h];
  }
  __syncthreads();
  if (t < 8) {
    float s1 = 0.f, s2 = 0.f;
    for (int d = 0; d < 128; ++d) {
      s1 += gws[d * 8 + t];
      s2 += b[d] * wp[d * 8 + t];
    }
    c1s[t] = s1;
    c2s[t] = s2;
  }
  __syncthreads();
  int pid = blockIdx.x * 256 + t;
  const float4* xp = (const float4*)(pair + (size_t)pid * 128);
  float sum = 0.f, sumsq = 0.f;
  float dots[8] = {};
#pragma unroll 8
  for (int i = 0; i < 32; ++i) {
    float4 v = xp[i];
#pragma unroll
    for (int j = 0; j < 4; ++j) {
      float e = (&v.x)[j];
      sum += e;
      sumsq = fmaf(e, e, sumsq);
      const float* gr = &gws[(i * 4 + j) * 8];
#pragma unroll
      for (int hh = 0; hh < 8; ++hh) dots[hh] = fmaf(e, gr[hh], dots[hh]);
    }
  }
  float mu = sum * (1.0f / 128.0f);
  float var = sumsq * (1.0f / 128.0f) - mu * mu;
  float rs = 1.0f / sqrtf(var + 1e-5f);
#pragma unroll
  for (int hh = 0; hh < 8; ++hh)
    pb[(size_t)hh * (L_ * L_) + pid] = rs * (dots[hh] - mu * c1s[hh]) + c2s[hh];
}

// ---------------------------------------------------------------------------
// softmax over last dim of (pb + sum of S split-K partials) -> attn bf16
// ---------------------------------------------------------------------------
__global__ __launch_bounds__(128) void sm_kernel(const float* __restrict__ pb,
                                                 const float* __restrict__ dp,
                                                 int S, __bf16* __restrict__ ab) {
  size_t row = blockIdx.x;
  int t = threadIdx.x;
  int wid = t >> 6;
  const float* p0 = pb + row * L_;
  float x0 = p0[t], x1 = p0[t + 128], x2 = p0[t + 256];
  const size_t HLL = (size_t)H_ * L_ * L_;
  for (int s = 0; s < S; ++s) {
    const float* ps = dp + s * HLL + row * L_;
    x0 += ps[t]; x1 += ps[t + 128]; x2 += ps[t + 256];
  }
  __shared__ float sm[2], ss[2];
  float m = wred_max(fmaxf(x0, fmaxf(x1, x2)));
  if ((t & 63) == 0) sm[wid] = m;
  __syncthreads();
  m = fmaxf(sm[0], sm[1]);
  float e0 = __expf(x0 - m), e1 = __expf(x1 - m), e2 = __expf(x2 - m);
  float s2 = wred_sum(e0 + e1 + e2);
  if ((t & 63) == 0) ss[wid] = s2;
  __syncthreads();
  float inv = 1.0f / (ss[0] + ss[1]);
  __bf16* op = ab + row * L_;
  op[t] = (__bf16)(e0 * inv);
  op[t + 128] = (__bf16)(e1 * inv);
  op[t + 256] = (__bf16)(e2 * inv);
}

// ---------------------------------------------------------------------------
// column attention, MFMA version
// ---------------------------------------------------------------------------
__global__ __launch_bounds__(256) void attw_kernel(const __bf16* __restrict__ qb,
                                                   const __bf16* __restrict__ kb,
                                                   const __bf16* __restrict__ vb,
                                                   __bf16* __restrict__ ob) {
  __shared__ __bf16 smem[27136];
  __bf16* Qs = smem;
  __bf16* Ks = smem + 9216;
  __bf16* Vt = smem + 18432;
  __bf16* Ps = smem;
  int bid = blockIdx.x;
  int lrel = bid >> 3, h = bid & 7;
  size_t base = (size_t)(lrel * H_ + h) * (128 * 64);
  int t = threadIdx.x;
#pragma unroll
  for (int u = 0; u < 4; ++u) {
    int flat = t + 256 * u;
    int row = flat >> 3, c8 = (flat & 7) << 3;
    *(uint4*)&Qs[row * 72 + c8] = *(const uint4*)&qb[base + (size_t)row * 64 + c8];
    *(uint4*)&Ks[row * 72 + c8] = *(const uint4*)&kb[base + (size_t)row * 64 + c8];
  }
#pragma unroll
  for (int u = 0; u < 4; ++u) {
    int idx = t + 256 * u;
    int r = idx & 127, c8 = (idx >> 7) << 3;
    bf16x8 v = *(const bf16x8*)&vb[base + (size_t)r * 64 + c8];
#pragma unroll
    for (int j = 0; j < 8; ++j) Vt[(c8 + j) * 136 + r] = v[j];
  }
  __syncthreads();

  const int lane = t & 63, w = t >> 6;
  const int lc = lane & 15, q8 = (lane >> 4) << 3;

  f32x4 s[2][8];
#pragma unroll
  for (int i = 0; i < 2; ++i)
#pragma unroll
    for (int n = 0; n < 8; ++n) s[i][n] = (f32x4){0.f, 0.f, 0.f, 0.f};
#pragma unroll
  for (int kt = 0; kt < 2; ++kt) {
    bf16x8 a[2];
#pragma unroll
    for (int i = 0; i < 2; ++i)
      a[i] = *(const bf16x8*)&Qs[(w * 32 + i * 16 + lc) * 72 + kt * 32 + q8];
#pragma unroll
    for (int n = 0; n < 8; ++n) {
      bf16x8 b = *(const bf16x8*)&Ks[(n * 16 + lc) * 72 + kt * 32 + q8];
#pragma unroll
      for (int i = 0; i < 2; ++i)
        s[i][n] = __builtin_amdgcn_mfma_f32_16x16x32_bf16(a[i], b, s[i][n], 0, 0, 0);
    }
  }

  float linv[2][4];
#pragma unroll
  for (int i = 0; i < 2; ++i) {
#pragma unroll
    for (int g = 0; g < 4; ++g) {
      float mx = -1e30f;
#pragma unroll
      for (int n = 0; n < 8; ++n) mx = fmaxf(mx, s[i][n][g]);
      mx = fmaxf(mx, __shfl_xor(mx, 1, 64));
      mx = fmaxf(mx, __shfl_xor(mx, 2, 64));
      mx = fmaxf(mx, __shfl_xor(mx, 4, 64));
      mx = fmaxf(mx, __shfl_xor(mx, 8, 64));
      float sum = 0.f;
#pragma unroll
      for (int n = 0; n < 8; ++n) {
        float e = __expf(0.125f * (s[i][n][g] - mx));
        s[i][n][g] = e;
        sum += e;
      }
      sum += __shfl_xor(sum, 1, 64);
      sum += __shfl_xor(sum, 2, 64);
      sum += __shfl_xor(sum, 4, 64);
      sum += __shfl_xor(sum, 8, 64);
      linv[i][g] = 1.0f / sum;
    }
  }
  __syncthreads();

#pragma unroll
  for (int i = 0; i < 2; ++i)
#pragma unroll
    for (int n = 0; n < 8; ++n)
#pragma unroll
      for (int g = 0; g < 4; ++g) {
        int row = w * 32 + i * 16 + ((lane >> 4) << 2) + g;
        int col = n * 16 + lc;
        Ps[row * 140 + col] = (__bf16)s[i][n][g];
      }
  __syncthreads();

  f32x4 o[2][4];
#pragma unroll
  for (int i = 0; i < 2; ++i)
#pragma unroll
    for (int n = 0; n < 4; ++n) o[i][n] = (f32x4){0.f, 0.f, 0.f, 0.f};
#pragma unroll
  for (int kt = 0; kt < 4; ++kt) {
    bf16x8 a[2];
#pragma unroll
    for (int i = 0; i < 2; ++i)
      a[i] = *(const bf16x8*)&Ps[(w * 32 + i * 16 + lc) * 140 + kt * 32 + q8];
#pragma unroll
    for (int n = 0; n < 4; ++n) {
      bf16x8 b = *(const bf16x8*)&Vt[(n * 16 + lc) * 136 + kt * 32 + q8];
#pragma unroll
      for (int i = 0; i < 2; ++i)
        o[i][n] = __builtin_amdgcn_mfma_f32_16x16x32_bf16(a[i], b, o[i][n], 0, 0, 0);
    }
  }

#pragma unroll
  for (int i = 0; i < 2; ++i)
#pragma unroll
    for (int n = 0; n < 4; ++n)
#pragma unroll
      for (int g = 0; g < 4; ++g) {
        int r = w * 32 + i * 16 + ((lane >> 4) << 2) + g;
        int dh = n * 16 + lc;
        ob[((size_t)(lrel * R_ + r)) * INNER_ + h * 64 + dh] =
            (__bf16)(o[i][n][g] * linv[i][g]);
      }
}

// ---------------------------------------------------------------------------
extern "C" void kernel_launch(void* const* d_in, const int* in_sizes, int n_in,
                              void* d_out, int out_size, void* d_ws,
                              size_t ws_size, hipStream_t stream) {
  (void)in_sizes; (void)n_in; (void)out_size;
  const float* m = (const float*)d_in[0];
  const float* pair = (const float*)d_in[1];
  const float* Wq_w = (const float*)d_in[2];
  const float* Wkv_w = (const float*)d_in[3];
  const float* Wo_w = (const float*)d_in[4];
  const float* bo_w = (const float*)d_in[5];
  const float* Wq_h = (const float*)d_in[6];
  const float* Wkv_h = (const float*)d_in[7];
  const float* Wo_h = (const float*)d_in[8];
  const float* bo_h = (const float*)d_in[9];
  const float* ln_g = (const float*)d_in[10];
  const float* ln_b = (const float*)d_in[11];
  const float* Wpair = (const float*)d_in[12];
  const float* Wsq = (const float*)d_in[13];
  const float* bsq = (const float*)d_in[14];
  const float* Wsk = (const float*)d_in[15];
  const float* bsk = (const float*)d_in[16];
  float* out = (float*)d_out;

  // ---- choose chunking (CH) and split count (S = 8/CH) to fit workspace ----
  const size_t fixedBase = 22446080u;
  int CH = 1;
  for (; CH < 8; CH *= 2) {
    size_t partials = (size_t)(8 / CH) * 4718592u;
    size_t o = 201326592u / CH;
    if (o < 25165824u) o = 25165824u;
    if (fixedBase + partials + o <= ws_size) break;
  }
  const int S = 8 / CH;
  const int Lc = L_ / CH;
  const int Rc = R_ / CH;

  unsigned char* base = (unsigned char*)d_ws;
  __bf16* m_bf = (__bf16*)base;       base += 12582912;
  __bf16* WTw = (__bf16*)base;        base += 393216;
  __bf16* WThqk = (__bf16*)base;      base += 262144;
  __bf16* WTvh = (__bf16*)base;       base += 131072;
  __bf16* WoTw = (__bf16*)base;       base += 131072;
  __bf16* WoTh = (__bf16*)base;       base += 131072;
  __bf16* WskT = (__bf16*)base;       base += 32768;
  __bf16* WsqT = (__bf16*)base;       base += 32768;
  float* wtie = (float*)base;         base += 1572864;
  float* pb = (float*)base;           base += 4718592;
  __bf16* attnb = (__bf16*)base;      base += 2359296;
  __bf16* qsb = (__bf16*)base;        base += 98304;
  float* dotsP = (float*)base;        base += (size_t)S * 4718592u;
  unsigned char* ovl = base;
  __bf16* ksb = (__bf16*)ovl;  // phase A only

  const size_t BUF = 25165824u / CH;
  __bf16* qb = (__bf16*)ovl;
  __bf16* kb = qb + BUF;
  __bf16* vb = kb + BUF;
  __bf16* ob = vb + BUF;

  prep_kernel<<<3208, 256, 0, stream>>>(m, m_bf, Wq_w, Wkv_w, Wq_h, Wkv_h, Wo_w,
                                        Wo_h, Wsk, Wsq, WTw, WThqk, WTvh, WoTw,
                                        WoTh, WskT, WsqT);

  // tie projections (ks rows 0..383, qs rows 384..386) + tie softmax + pair bias
  mm_k<8><<<dim3(1, 387), 256, 0, stream>>>(m_bf, WskT, bsk, bsq, ksb, qsb, WsqT,
                                            nullptr, 128, 0, Rc, 0, 0, 1);
  tie_kernel<<<L_ * H_, 128, 0, stream>>>(qsb, ksb, wtie);
  lnpb_kernel<<<(L_ * L_) / 256, 256, 0, stream>>>(pair, ln_g, ln_b, Wpair, pb);

  for (int c = 0; c < CH; ++c) {
    int l0 = c * Lc;
    mm_k<0><<<dim3(12, Lc), 256, 0, stream>>>(m_bf, WTw, nullptr, nullptr, qb, kb, vb,
                                              nullptr, 128, l0, Rc, 0, 0, 1);
    attw_kernel<<<Lc * H_, 256, 0, stream>>>(qb, kb, vb, ob);
    mm_k<4><<<dim3(1, Lc), 256, 0, stream>>>(ob, WoTw, bo_w, nullptr, nullptr, nullptr,
                                             nullptr, out, 512, l0, Rc, 0, 0, 1);
  }

  for (int c = 0; c < CH; ++c) {
    int r0 = c * Rc;
    mm_k<1><<<dim3(8, Rc * 3), 256, 0, stream>>>(m_bf, WThqk, nullptr, wtie, qb, kb,
                                                 nullptr, nullptr, 128, r0, Rc, 0, 0, 1);
    mm_k<2><<<9 * H_ * S, 256, 0, stream>>>(qb, kb, nullptr, nullptr, nullptr,
                                            nullptr, nullptr, dotsP,
                                            (Rc * 64) / S, r0, Rc, Rc * 64,
                                            (c == 0) ? 1 : 0, S);
  }
  sm_kernel<<<H_ * L_, 128, 0, stream>>>(pb, dotsP, S, attnb);

  for (int c = 0; c < CH; ++c) {
    int r0 = c * Rc;
    mm_k<6><<<dim3(3, 4, Rc), 256, 0, stream>>>(WTvh, m_bf, nullptr, nullptr, vb, nullptr,
                                                nullptr, nullptr, 128, r0, Rc, 0, 0, 1);
    mm_k<3><<<dim3(Rc / 2, 3, 8), 256, 0, stream>>>(attnb, vb, nullptr, nullptr, ob, nullptr,
                                                    nullptr, nullptr, 384, r0, Rc, 0, 0, 1);
    mm_k<5><<<dim3(1, Rc * 3), 256, 0, stream>>>(ob, WoTh, bo_h, nullptr, nullptr, nullptr,
                                                 nullptr, out, 512, r0, Rc, 0, 0, 1);
  }
}

// Round 7
// 511.709 us; speedup vs baseline: 1.0965x; 1.0965x over previous
//
#include <hip/hip_runtime.h>
#include <math.h>

#define L_ 384
#define R_ 128
#define D_ 128
#define H_ 8
#define DH_ 64
#define INNER_ 512

typedef __bf16 bf16x8 __attribute__((ext_vector_type(8)));
typedef float f32x4 __attribute__((ext_vector_type(4)));

__device__ __forceinline__ float wred_sum(float v) {
#pragma unroll
  for (int o = 32; o > 0; o >>= 1) v += __shfl_xor(v, o, 64);
  return v;
}
__device__ __forceinline__ float wred_max(float v) {
#pragma unroll
  for (int o = 32; o > 0; o >>= 1) v = fmaxf(v, __shfl_xor(v, o, 64));
  return v;
}

// ---------------------------------------------------------------------------
// prep: m fp32->bf16 (blocks 0..3071) + all weight transposes (blocks 3072..3207)
// ---------------------------------------------------------------------------
__global__ __launch_bounds__(256) void prep_kernel(
    const float* __restrict__ m, __bf16* __restrict__ m_bf,
    const float* __restrict__ Wq_w, const float* __restrict__ Wkv_w,
    const float* __restrict__ Wq_h, const float* __restrict__ Wkv_h,
    const float* __restrict__ Wo_w, const float* __restrict__ Wo_h,
    const float* __restrict__ Wsk, const float* __restrict__ Wsq,
    __bf16* __restrict__ WTw, __bf16* __restrict__ WThqk,
    __bf16* __restrict__ WTvh, __bf16* __restrict__ WoTw,
    __bf16* __restrict__ WoTh, __bf16* __restrict__ WskT,
    __bf16* __restrict__ WsqT) {
  __shared__ float Ls[64 * 65];
  int b = blockIdx.x;
  int t = threadIdx.x;
  if (b < 3072) {
    int i = b * 256 + t;
    float4 a = *(const float4*)(m + (size_t)i * 8);
    float4 c = *(const float4*)(m + (size_t)i * 8 + 4);
    bf16x8 o;
    o[0] = (__bf16)a.x; o[1] = (__bf16)a.y; o[2] = (__bf16)a.z; o[3] = (__bf16)a.w;
    o[4] = (__bf16)c.x; o[5] = (__bf16)c.y; o[6] = (__bf16)c.z; o[7] = (__bf16)c.w;
    *(uint4*)(m_bf + (size_t)i * 8) = __builtin_bit_cast(uint4, o);
    return;
  }
  int j = b - 3072;
  const float* src; __bf16* dst; int Kd, Ns, noff, gx, base;
  if (j < 16)       { src = Wq_w;  dst = WTw;             Kd = 128; Ns = 512;  noff = 0;   gx = 8;  base = 0; }
  else if (j < 48)  { src = Wkv_w; dst = WTw + 512 * 128; Kd = 128; Ns = 1024; noff = 0;   gx = 16; base = 16; }
  else if (j < 64)  { src = Wq_h;  dst = WThqk;           Kd = 128; Ns = 512;  noff = 0;   gx = 8;  base = 48; }
  else if (j < 80)  { src = Wkv_h; dst = WThqk + 512 * 128; Kd = 128; Ns = 1024; noff = 0; gx = 8;  base = 64; }
  else if (j < 96)  { src = Wkv_h; dst = WTvh;            Kd = 128; Ns = 1024; noff = 512; gx = 8;  base = 80; }
  else if (j < 112) { src = Wo_w;  dst = WoTw;            Kd = 512; Ns = 128;  noff = 0;   gx = 2;  base = 96; }
  else if (j < 128) { src = Wo_h;  dst = WoTh;            Kd = 512; Ns = 128;  noff = 0;   gx = 2;  base = 112; }
  else if (j < 132) { src = Wsk;   dst = WskT;            Kd = 128; Ns = 128;  noff = 0;   gx = 2;  base = 128; }
  else              { src = Wsq;   dst = WsqT;            Kd = 128; Ns = 128;  noff = 0;   gx = 2;  base = 132; }
  int jl = j - base;
  int n0 = (jl % gx) * 64, k0 = (jl / gx) * 64;
#pragma unroll
  for (int u = 0; u < 4; ++u) {
    int flat = t + 256 * u;
    int kr = flat >> 4, nc = (flat & 15) * 4;
    float4 v = *(const float4*)&src[(size_t)(k0 + kr) * Ns + noff + n0 + nc];
    Ls[kr * 65 + nc + 0] = v.x;
    Ls[kr * 65 + nc + 1] = v.y;
    Ls[kr * 65 + nc + 2] = v.z;
    Ls[kr * 65 + nc + 3] = v.w;
  }
  __syncthreads();
#pragma unroll
  for (int u = 0; u < 2; ++u) {
    int flat = t + 256 * u;
    int nr = flat >> 3, kc = (flat & 7) * 8;
    bf16x8 o;
#pragma unroll
    for (int q = 0; q < 8; ++q) o[q] = (__bf16)Ls[(kc + q) * 65 + nr];
    *(uint4*)&dst[(size_t)(n0 + nr) * Kd + k0 + kc] = __builtin_bit_cast(uint4, o);
  }
}

// ---------------------------------------------------------------------------
// bf16 MFMA GEMM, 128x128 tile, BK=64, 256 threads (4 waves 2x2), 16x16x32 mfma.
// Round-5 proven staging (manual uint4 -> padded LDS).
// MODE 0: PROJ_W   A=m_bf gathered (l,r), B=WTw, C->q/k/v w-layout bf16
// MODE 1: PROJ_H   A=m_bf, B=WThqk, C->qh (tie-scaled via LDS-staged tie) / kh
// MODE 2: DOTS     pure NT GEMM, 1D XCD-swizzled grid, split-K partials fp32
// MODE 3: OH       A=attnb[h][L][L], B=vt[h][n][L], C->ob bf16
// MODE 4: OUT_W    C = 0.5*(acc+bias) -> out fp32
// MODE 5: OUT_H    C += 0.5*(acc+bias) -> out fp32
// MODE 6: PROJ_VT  A=WTvh, B=m_bf rows, C->vt bf16 (transposed v)
// MODE 8: TIE PROJ ks (m0<49152) / qs (m0>=49152, B=O2=WsqT, bias=tie=bsq)
// ---------------------------------------------------------------------------
template <int MODE>
__global__ __launch_bounds__(256) void mm_k(
    const __bf16* __restrict__ A, const __bf16* __restrict__ B,
    const float* __restrict__ bias, const float* __restrict__ tie,
    __bf16* __restrict__ O0, __bf16* __restrict__ O1, __bf16* __restrict__ O2,
    float* __restrict__ F0,
    int K, int c0, int Rc, int KT, int firstChunk, int S) {
  __shared__ __bf16 As[128 * 72];
  __shared__ __bf16 Bs[128 * 72];
  const int t = threadIdx.x;
  const int lane = t & 63, w = t >> 6;
  const int wm = w >> 1, wn = w & 1;
  int n0, m0, h = 0, s = 0, kOff = 0;
  const int bz = blockIdx.z;
  if (MODE == 2) {
    int b = blockIdx.x;
    int xcd = b & 7, t2 = b >> 3;
    int i3 = t2 % 3, slot = t2 / 3;
    int g = xcd * (gridDim.x / 24) + slot;
    n0 = i3 * 128;
    m0 = (g % 3) * 128;
    int z = g / 3;
    h = z / S; s = z % S; kOff = s * K;
  } else {
    n0 = blockIdx.x * 128;
    m0 = blockIdx.y * 128;
    if (MODE == 3) h = bz;
  }
  const int pbase = (MODE == 8 && m0 >= 49152) ? 49152 : 0;
  const __bf16* Bmat = (MODE == 8 && pbase) ? (const __bf16*)O2 : B;

  f32x4 acc[4][4];
#pragma unroll
  for (int i = 0; i < 4; ++i)
#pragma unroll
    for (int j = 0; j < 4; ++j) acc[i][j] = (f32x4){0.f, 0.f, 0.f, 0.f};

  for (int k0 = 0; k0 < K; k0 += 64) {
#pragma unroll
    for (int u = 0; u < 4; ++u) {
      int flat = t + 256 * u;
      int row = flat >> 3;
      int c8 = (flat & 7) << 3;
      const __bf16* ap;
      int p = m0 + row;
      if (MODE == 0) { int lrel = p >> 7, rr = p & 127;
        ap = A + ((size_t)(rr * L_ + c0 + lrel)) * 128 + k0 + c8; }
      else if (MODE == 1) ap = A + ((size_t)(c0 * L_ + p)) * 128 + k0 + c8;
      else if (MODE == 2) ap = A + ((size_t)(h * L_ + p)) * KT + kOff + k0 + c8;
      else if (MODE == 3) ap = A + ((size_t)(h * L_ + p)) * L_ + k0 + c8;
      else if (MODE == 4) ap = A + (size_t)p * INNER_ + k0 + c8;
      else if (MODE == 5) { int rrel = p / L_, l = p - rrel * L_;
        ap = A + (((size_t)((k0 >> 6) * L_ + l)) * Rc + rrel) * 64 + c8; }
      else if (MODE == 8) ap = A + (size_t)(p - pbase) * 128 + k0 + c8;
      else ap = A + (size_t)p * 128 + k0 + c8;
      *(uint4*)&As[row * 72 + c8] = *(const uint4*)ap;
      const __bf16* bp;
      int n = n0 + row;
      if (MODE == 0 || MODE == 1 || MODE == 8) bp = Bmat + (size_t)n * 128 + k0 + c8;
      else if (MODE == 2) bp = B + ((size_t)(h * L_ + n)) * KT + kOff + k0 + c8;
      else if (MODE == 3) bp = B + ((size_t)(h * Rc * 64 + n)) * L_ + k0 + c8;
      else if (MODE == 4 || MODE == 5) bp = B + (size_t)n * INNER_ + k0 + c8;
      else bp = B + ((size_t)((c0 + bz) * L_ + n)) * 128 + k0 + c8;
      *(uint4*)&Bs[row * 72 + c8] = *(const uint4*)bp;
    }
    __syncthreads();
    {
      int lc = lane & 15, q8 = (lane >> 4) << 3;
#pragma unroll
      for (int kt = 0; kt < 2; ++kt) {
        bf16x8 af[4], bfr[4];
#pragma unroll
        for (int i = 0; i < 4; ++i) {
          af[i] = *(const bf16x8*)&As[(wm * 64 + i * 16 + lc) * 72 + kt * 32 + q8];
          bfr[i] = *(const bf16x8*)&Bs[(wn * 64 + i * 16 + lc) * 72 + kt * 32 + q8];
        }
#pragma unroll
        for (int i = 0; i < 4; ++i)
#pragma unroll
          for (int j = 0; j < 4; ++j)
            acc[i][j] = __builtin_amdgcn_mfma_f32_16x16x32_bf16(af[i], bfr[j], acc[i][j], 0, 0, 0);
      }
    }
    __syncthreads();
  }

  // MODE 1 (qh blocks): cooperatively stage the 256 tie weights into LDS
  float* tieS = (float*)As;  // safe: all LDS reads done (barrier above)
  if (MODE == 1 && n0 < 512) {
    int row = t >> 1, hh2 = t & 1;
    int pm = m0 + row;
    int rrel = pm / L_, l = pm - rrel * L_;
    int h0 = n0 >> 6;
    tieS[row * 2 + hh2] = tie[((size_t)(l * H_ + h0 + hh2)) * R_ + c0 + rrel];
    __syncthreads();
  }

  int lce = lane & 15, lr4 = (lane >> 4) << 2;
#pragma unroll
  for (int i = 0; i < 4; ++i) {
#pragma unroll
    for (int j = 0; j < 4; ++j) {
#pragma unroll
      for (int g = 0; g < 4; ++g) {
        int pm = m0 + wm * 64 + i * 16 + lr4 + g;
        int pn = n0 + wn * 64 + j * 16 + lce;
        float v = acc[i][j][g];
        if (MODE == 0) {
          __bf16* buf;
          int nn = pn;
          if (nn < 512) buf = O0;
          else if (nn < 1024) { buf = O1; nn -= 512; }
          else { buf = O2; nn -= 1024; }
          int hh = nn >> 6, dh = nn & 63;
          int lrel = pm >> 7, rr = pm & 127;
          buf[(((size_t)(lrel * H_ + hh)) * R_ + rr) * 64 + dh] = (__bf16)v;
        } else if (MODE == 1) {
          int nn = pn;
          int rrel = pm / L_, l = pm - rrel * L_;
          if (nn < 512) {  // qh, tie-scaled
            int hh = nn >> 6, dh = nn & 63;
            float tw = tieS[(pm - m0) * 2 + (hh - (n0 >> 6))];
            O0[(((size_t)(hh * L_ + l)) * Rc + rrel) * 64 + dh] = (__bf16)(v * tw);
          } else {
            nn -= 512;
            int hh = nn >> 6, dh = nn & 63;
            O1[(((size_t)(hh * L_ + l)) * Rc + rrel) * 64 + dh] = (__bf16)v;
          }
        } else if (MODE == 2) {
          float* ptr = F0 + ((size_t)(s * H_ + h)) * (L_ * L_) + (size_t)pm * L_ + pn;
          float val = 0.125f * v;
          if (firstChunk) *ptr = val;
          else *ptr += val;
        } else if (MODE == 3) {
          O0[((size_t)(h * L_ + pm)) * ((size_t)Rc * 64) + pn] = (__bf16)v;
        } else if (MODE == 4) {
          int lrel = pm >> 7, rr = pm & 127;
          F0[((size_t)(rr * L_ + c0 + lrel)) * 128 + pn] = 0.5f * (v + bias[pn]);
        } else if (MODE == 5) {
          int rrel = pm / L_, l = pm - rrel * L_;
          float* ptr = F0 + ((size_t)((c0 + rrel) * L_ + l)) * 128 + pn;
          *ptr += 0.5f * (v + bias[pn]);
        } else if (MODE == 8) {
          const float* bb = pbase ? tie : bias;
          __bf16* dst = pbase ? O1 : O0;
          dst[(size_t)(pm - pbase) * 128 + pn] = (__bf16)(v + bb[pn]);
        } else {
          O0[(((size_t)((pm >> 6) * Rc + bz)) * 64 + (pm & 63)) * (size_t)L_ + pn] = (__bf16)v;
        }
      }
    }
  }
}

// ---------------------------------------------------------------------------
// tie softmax (bf16 inputs)
// ---------------------------------------------------------------------------
__global__ __launch_bounds__(128) void tie_kernel(const __bf16* __restrict__ qs,
                                                  const __bf16* __restrict__ ks,
                                                  float* __restrict__ wtie) {
  int bid = blockIdx.x;
  int l = bid >> 3, h = bid & 7;
  int r = threadIdx.x;
  int wid = r >> 6;
  const __bf16* qp = qs + (size_t)l * 128 + h * 16;
  const __bf16* kp = ks + ((size_t)r * L_ + l) * 128 + h * 16;
  bf16x8 q0 = *(const bf16x8*)qp;
  bf16x8 q1 = *(const bf16x8*)(qp + 8);
  bf16x8 k0 = *(const bf16x8*)kp;
  bf16x8 k1 = *(const bf16x8*)(kp + 8);
  float s = 0.f;
#pragma unroll
  for (int i = 0; i < 8; ++i)
    s += (float)q0[i] * (float)k0[i] + (float)q1[i] * (float)k1[i];
  s *= 0.25f;
  __shared__ float sm[2], ss[2];
  float wm = wred_max(s);
  if ((r & 63) == 0) sm[wid] = wm;
  __syncthreads();
  float mx = fmaxf(sm[0], sm[1]);
  float e = __expf(s - mx);
  float wsum = wred_sum(e);
  if ((r & 63) == 0) ss[wid] = wsum;
  __syncthreads();
  float tot = ss[0] + ss[1];
  wtie[((size_t)l * H_ + h) * R_ + r] = e / tot;
}

// ---------------------------------------------------------------------------
// pair LN + Wpair -> pb[h][i][j]. One THREAD per (i,j); no cross-lane ops.
// ---------------------------------------------------------------------------
__global__ __launch_bounds__(256) void lnpb_kernel(const float* __restrict__ pair,
                                                   const float* __restrict__ g,
                                                   const float* __restrict__ b,
                                                   const float* __restrict__ wp,
                                                   float* __restrict__ pb) {
  __shared__ float gws[1024];
  __shared__ float c1s[8], c2s[8];
  int t = threadIdx.x;
#pragma unroll
  for (int u = 0; u < 4; ++u) {
    int idx = t * 4 + u;
    int d = idx >> 3, h = idx & 7;
    gws[idx] = g[d] * wp[d * 8 + h];
  }
  __syncthreads();
  if (t < 8) {
    float s1 = 0.f, s2 = 0.f;
    for (int d = 0; d < 128; ++d) {
      s1 += gws[d * 8 + t];
      s2 += b[d] * wp[d * 8 + t];
    }
    c1s[t] = s1;
    c2s[t] = s2;
  }
  __syncthreads();
  int pid = blockIdx.x * 256 + t;
  const float4* xp = (const float4*)(pair + (size_t)pid * 128);
  float sum = 0.f, sumsq = 0.f;
  float dots[8] = {};
#pragma unroll 8
  for (int i = 0; i < 32; ++i) {
    float4 v = xp[i];
#pragma unroll
    for (int j = 0; j < 4; ++j) {
      float e = (&v.x)[j];
      sum += e;
      sumsq = fmaf(e, e, sumsq);
      const float* gr = &gws[(i * 4 + j) * 8];
#pragma unroll
      for (int hh = 0; hh < 8; ++hh) dots[hh] = fmaf(e, gr[hh], dots[hh]);
    }
  }
  float mu = sum * (1.0f / 128.0f);
  float var = sumsq * (1.0f / 128.0f) - mu * mu;
  float rs = 1.0f / sqrtf(var + 1e-5f);
#pragma unroll
  for (int hh = 0; hh < 8; ++hh)
    pb[(size_t)hh * (L_ * L_) + pid] = rs * (dots[hh] - mu * c1s[hh]) + c2s[hh];
}

// ---------------------------------------------------------------------------
// softmax over last dim of (pb + sum of S split-K partials) -> attn bf16
// ---------------------------------------------------------------------------
__global__ __launch_bounds__(128) void sm_kernel(const float* __restrict__ pb,
                                                 const float* __restrict__ dp,
                                                 int S, __bf16* __restrict__ ab) {
  size_t row = blockIdx.x;
  int t = threadIdx.x;
  int wid = t >> 6;
  const float* p0 = pb + row * L_;
  float x0 = p0[t], x1 = p0[t + 128], x2 = p0[t + 256];
  const size_t HLL = (size_t)H_ * L_ * L_;
  for (int s = 0; s < S; ++s) {
    const float* ps = dp + s * HLL + row * L_;
    x0 += ps[t]; x1 += ps[t + 128]; x2 += ps[t + 256];
  }
  __shared__ float sm[2], ss[2];
  float m = wred_max(fmaxf(x0, fmaxf(x1, x2)));
  if ((t & 63) == 0) sm[wid] = m;
  __syncthreads();
  m = fmaxf(sm[0], sm[1]);
  float e0 = __expf(x0 - m), e1 = __expf(x1 - m), e2 = __expf(x2 - m);
  float s2 = wred_sum(e0 + e1 + e2);
  if ((t & 63) == 0) ss[wid] = s2;
  __syncthreads();
  float inv = 1.0f / (ss[0] + ss[1]);
  __bf16* op = ab + row * L_;
  op[t] = (__bf16)(e0 * inv);
  op[t + 128] = (__bf16)(e1 * inv);
  op[t + 256] = (__bf16)(e2 * inv);
}

// ---------------------------------------------------------------------------
// column attention, MFMA version
// ---------------------------------------------------------------------------
__global__ __launch_bounds__(256) void attw_kernel(const __bf16* __restrict__ qb,
                                                   const __bf16* __restrict__ kb,
                                                   const __bf16* __restrict__ vb,
                                                   __bf16* __restrict__ ob) {
  __shared__ __bf16 smem[27136];
  __bf16* Qs = smem;
  __bf16* Ks = smem + 9216;
  __bf16* Vt = smem + 18432;
  __bf16* Ps = smem;
  int bid = blockIdx.x;
  int lrel = bid >> 3, h = bid & 7;
  size_t base = (size_t)(lrel * H_ + h) * (128 * 64);
  int t = threadIdx.x;
#pragma unroll
  for (int u = 0; u < 4; ++u) {
    int flat = t + 256 * u;
    int row = flat >> 3, c8 = (flat & 7) << 3;
    *(uint4*)&Qs[row * 72 + c8] = *(const uint4*)&qb[base + (size_t)row * 64 + c8];
    *(uint4*)&Ks[row * 72 + c8] = *(const uint4*)&kb[base + (size_t)row * 64 + c8];
  }
#pragma unroll
  for (int u = 0; u < 4; ++u) {
    int idx = t + 256 * u;
    int r = idx & 127, c8 = (idx >> 7) << 3;
    bf16x8 v = *(const bf16x8*)&vb[base + (size_t)r * 64 + c8];
#pragma unroll
    for (int j = 0; j < 8; ++j) Vt[(c8 + j) * 136 + r] = v[j];
  }
  __syncthreads();

  const int lane = t & 63, w = t >> 6;
  const int lc = lane & 15, q8 = (lane >> 4) << 3;

  f32x4 s[2][8];
#pragma unroll
  for (int i = 0; i < 2; ++i)
#pragma unroll
    for (int n = 0; n < 8; ++n) s[i][n] = (f32x4){0.f, 0.f, 0.f, 0.f};
#pragma unroll
  for (int kt = 0; kt < 2; ++kt) {
    bf16x8 a[2];
#pragma unroll
    for (int i = 0; i < 2; ++i)
      a[i] = *(const bf16x8*)&Qs[(w * 32 + i * 16 + lc) * 72 + kt * 32 + q8];
#pragma unroll
    for (int n = 0; n < 8; ++n) {
      bf16x8 b = *(const bf16x8*)&Ks[(n * 16 + lc) * 72 + kt * 32 + q8];
#pragma unroll
      for (int i = 0; i < 2; ++i)
        s[i][n] = __builtin_amdgcn_mfma_f32_16x16x32_bf16(a[i], b, s[i][n], 0, 0, 0);
    }
  }

  float linv[2][4];
#pragma unroll
  for (int i = 0; i < 2; ++i) {
#pragma unroll
    for (int g = 0; g < 4; ++g) {
      float mx = -1e30f;
#pragma unroll
      for (int n = 0; n < 8; ++n) mx = fmaxf(mx, s[i][n][g]);
      mx = fmaxf(mx, __shfl_xor(mx, 1, 64));
      mx = fmaxf(mx, __shfl_xor(mx, 2, 64));
      mx = fmaxf(mx, __shfl_xor(mx, 4, 64));
      mx = fmaxf(mx, __shfl_xor(mx, 8, 64));
      float sum = 0.f;
#pragma unroll
      for (int n = 0; n < 8; ++n) {
        float e = __expf(0.125f * (s[i][n][g] - mx));
        s[i][n][g] = e;
        sum += e;
      }
      sum += __shfl_xor(sum, 1, 64);
      sum += __shfl_xor(sum, 2, 64);
      sum += __shfl_xor(sum, 4, 64);
      sum += __shfl_xor(sum, 8, 64);
      linv[i][g] = 1.0f / sum;
    }
  }
  __syncthreads();

#pragma unroll
  for (int i = 0; i < 2; ++i)
#pragma unroll
    for (int n = 0; n < 8; ++n)
#pragma unroll
      for (int g = 0; g < 4; ++g) {
        int row = w * 32 + i * 16 + ((lane >> 4) << 2) + g;
        int col = n * 16 + lc;
        Ps[row * 140 + col] = (__bf16)s[i][n][g];
      }
  __syncthreads();

  f32x4 o[2][4];
#pragma unroll
  for (int i = 0; i < 2; ++i)
#pragma unroll
    for (int n = 0; n < 4; ++n) o[i][n] = (f32x4){0.f, 0.f, 0.f, 0.f};
#pragma unroll
  for (int kt = 0; kt < 4; ++kt) {
    bf16x8 a[2];
#pragma unroll
    for (int i = 0; i < 2; ++i)
      a[i] = *(const bf16x8*)&Ps[(w * 32 + i * 16 + lc) * 140 + kt * 32 + q8];
#pragma unroll
    for (int n = 0; n < 4; ++n) {
      bf16x8 b = *(const bf16x8*)&Vt[(n * 16 + lc) * 136 + kt * 32 + q8];
#pragma unroll
      for (int i = 0; i < 2; ++i)
        o[i][n] = __builtin_amdgcn_mfma_f32_16x16x32_bf16(a[i], b, o[i][n], 0, 0, 0);
    }
  }

#pragma unroll
  for (int i = 0; i < 2; ++i)
#pragma unroll
    for (int n = 0; n < 4; ++n)
#pragma unroll
      for (int g = 0; g < 4; ++g) {
        int r = w * 32 + i * 16 + ((lane >> 4) << 2) + g;
        int dh = n * 16 + lc;
        ob[((size_t)(lrel * R_ + r)) * INNER_ + h * 64 + dh] =
            (__bf16)(o[i][n][g] * linv[i][g]);
      }
}

// ---------------------------------------------------------------------------
extern "C" void kernel_launch(void* const* d_in, const int* in_sizes, int n_in,
                              void* d_out, int out_size, void* d_ws,
                              size_t ws_size, hipStream_t stream) {
  (void)in_sizes; (void)n_in; (void)out_size;
  const float* m = (const float*)d_in[0];
  const float* pair = (const float*)d_in[1];
  const float* Wq_w = (const float*)d_in[2];
  const float* Wkv_w = (const float*)d_in[3];
  const float* Wo_w = (const float*)d_in[4];
  const float* bo_w = (const float*)d_in[5];
  const float* Wq_h = (const float*)d_in[6];
  const float* Wkv_h = (const float*)d_in[7];
  const float* Wo_h = (const float*)d_in[8];
  const float* bo_h = (const float*)d_in[9];
  const float* ln_g = (const float*)d_in[10];
  const float* ln_b = (const float*)d_in[11];
  const float* Wpair = (const float*)d_in[12];
  const float* Wsq = (const float*)d_in[13];
  const float* bsq = (const float*)d_in[14];
  const float* Wsk = (const float*)d_in[15];
  const float* bsk = (const float*)d_in[16];
  float* out = (float*)d_out;

  // ---- choose chunking (CH) and split count (S = 8/CH) to fit workspace ----
  const size_t fixedBase = 22446080u;
  int CH = 1;
  for (; CH < 8; CH *= 2) {
    size_t partials = (size_t)(8 / CH) * 4718592u;
    size_t o = 201326592u / CH;
    if (o < 25165824u) o = 25165824u;
    if (fixedBase + partials + o <= ws_size) break;
  }
  const int S = 8 / CH;
  const int Lc = L_ / CH;
  const int Rc = R_ / CH;

  unsigned char* base = (unsigned char*)d_ws;
  __bf16* m_bf = (__bf16*)base;       base += 12582912;
  __bf16* WTw = (__bf16*)base;        base += 393216;
  __bf16* WThqk = (__bf16*)base;      base += 262144;
  __bf16* WTvh = (__bf16*)base;       base += 131072;
  __bf16* WoTw = (__bf16*)base;       base += 131072;
  __bf16* WoTh = (__bf16*)base;       base += 131072;
  __bf16* WskT = (__bf16*)base;       base += 32768;
  __bf16* WsqT = (__bf16*)base;       base += 32768;
  float* wtie = (float*)base;         base += 1572864;
  float* pb = (float*)base;           base += 4718592;
  __bf16* attnb = (__bf16*)base;      base += 2359296;
  __bf16* qsb = (__bf16*)base;        base += 98304;
  float* dotsP = (float*)base;        base += (size_t)S * 4718592u;
  unsigned char* ovl = base;
  __bf16* ksb = (__bf16*)ovl;  // phase A only

  const size_t BUF = 25165824u / CH;
  __bf16* qb = (__bf16*)ovl;
  __bf16* kb = qb + BUF;
  __bf16* vb = kb + BUF;
  __bf16* ob = vb + BUF;

  prep_kernel<<<3208, 256, 0, stream>>>(m, m_bf, Wq_w, Wkv_w, Wq_h, Wkv_h, Wo_w,
                                        Wo_h, Wsk, Wsq, WTw, WThqk, WTvh, WoTw,
                                        WoTh, WskT, WsqT);

  // tie projections (ks rows 0..383 tiles, qs rows 384..386) + softmax + pair bias
  mm_k<8><<<dim3(1, 387), 256, 0, stream>>>(m_bf, WskT, bsk, bsq, ksb, qsb, WsqT,
                                            nullptr, 128, 0, Rc, 0, 0, 1);
  tie_kernel<<<L_ * H_, 128, 0, stream>>>(qsb, ksb, wtie);
  lnpb_kernel<<<(L_ * L_) / 256, 256, 0, stream>>>(pair, ln_g, ln_b, Wpair, pb);

  for (int c = 0; c < CH; ++c) {
    int l0 = c * Lc;
    mm_k<0><<<dim3(12, Lc), 256, 0, stream>>>(m_bf, WTw, nullptr, nullptr, qb, kb, vb,
                                              nullptr, 128, l0, Rc, 0, 0, 1);
    attw_kernel<<<Lc * H_, 256, 0, stream>>>(qb, kb, vb, ob);
    mm_k<4><<<dim3(1, Lc), 256, 0, stream>>>(ob, WoTw, bo_w, nullptr, nullptr, nullptr,
                                             nullptr, out, 512, l0, Rc, 0, 0, 1);
  }

  for (int c = 0; c < CH; ++c) {
    int r0 = c * Rc;
    mm_k<1><<<dim3(8, Rc * 3), 256, 0, stream>>>(m_bf, WThqk, nullptr, wtie, qb, kb,
                                                 nullptr, nullptr, 128, r0, Rc, 0, 0, 1);
    mm_k<2><<<9 * H_ * S, 256, 0, stream>>>(qb, kb, nullptr, nullptr, nullptr,
                                            nullptr, nullptr, dotsP,
                                            (Rc * 64) / S, r0, Rc, Rc * 64,
                                            (c == 0) ? 1 : 0, S);
  }
  sm_kernel<<<H_ * L_, 128, 0, stream>>>(pb, dotsP, S, attnb);

  for (int c = 0; c < CH; ++c) {
    int r0 = c * Rc;
    mm_k<6><<<dim3(3, 4, Rc), 256, 0, stream>>>(WTvh, m_bf, nullptr, nullptr, vb, nullptr,
                                                nullptr, nullptr, 128, r0, Rc, 0, 0, 1);
    mm_k<3><<<dim3(Rc / 2, 3, 8), 256, 0, stream>>>(attnb, vb, nullptr, nullptr, ob, nullptr,
                                                    nullptr, nullptr, 384, r0, Rc, 0, 0, 1);
    mm_k<5><<<dim3(1, Rc * 3), 256, 0, stream>>>(ob, WoTh, bo_h, nullptr, nullptr, nullptr,
                                                 nullptr, out, 512, r0, Rc, 0, 0, 1);
  }
}